// Round 5
// baseline (1085.521 us; speedup 1.0000x reference)
//
#include <hip/hip_runtime.h>

#define TPB 256
#define RNG 128          // nodes per range
#define RSH 7            // log2(RNG)
#define MAXC 1024        // max ranges supported by LDS hist (N <= 131072)
#define EPB 2048         // edges per block in hist/place

// ---------------------------------------------------------------------------
// GCN via (A_norm)(h W) = (A_norm h) W.
// Aggregation: edges counting-sorted into 782 dst-ranges of 128 nodes
// (XCD-sharded writes -> no line write-amp), then range-owning workgroups
// accumulate into LDS fp32 accumulators (ds_add_f32), dense write-out.
//   hsx  = dinv * x                              [N,16]
//   agg16[d] = hsx[d] + sum_{s->d} hsx[s]
//   hs1  = dinv * relu(dinv * agg16 @ W1 + b1)   [N,64]
//   acc1[d] = hs1[d] + sum_{s->d} hs1[s]
//   out  = dinv*acc1 @ (W2@WL) + (b2@WL + bL)
// ---------------------------------------------------------------------------

// Wf[k][o] = sum_j W2[k][j]*WL[j][o]; bf[o] = sum_j b2[j]*WL[j][o] + bL[o]
__global__ void k_wfuse(const float* __restrict__ W2, const float* __restrict__ WL,
                        const float* __restrict__ b2, const float* __restrict__ bL,
                        float* __restrict__ Wf, float* __restrict__ bf) {
    int gid = blockIdx.x * TPB + threadIdx.x;     // 4 blocks * 256 = 1024 = 64*16
    int k = gid >> 4, o = gid & 15;
    if (k < 64) {
        float s = 0.f;
#pragma unroll 8
        for (int j = 0; j < 128; j++) s += W2[k * 128 + j] * WL[j * 16 + o];
        Wf[gid] = s;
    }
    if (gid < 16) {
        float s = bL[gid];
        for (int j = 0; j < 128; j++) s += b2[j] * WL[j * 16 + gid];
        bf[gid] = s;
    }
}

// per-block LDS histogram of dst-range, merged into ghist[c*8 + shard]
__global__ void k_hist(const int* __restrict__ ei, int* __restrict__ ghist,
                       int E, int C) {
    __shared__ int h[MAXC];
    int t = threadIdx.x, b = blockIdx.x, j = b & 7;
    for (int c = t; c < C; c += TPB) h[c] = 0;
    __syncthreads();
    int base = b * EPB;
#pragma unroll
    for (int it = 0; it < EPB / TPB; it++) {
        int e = base + it * TPB + t;
        if (e < E) atomicAdd(&h[ei[E + e] >> RSH], 1);
    }
    __syncthreads();
    for (int c = t; c < C; c += TPB) {
        int v = h[c];
        if (v) atomicAdd(&ghist[c * 8 + j], v);
    }
}

// single-block exclusive scan of ghist[0..L) -> gbase (+sentinel), gcur copy
__global__ void k_scan(const int* __restrict__ ghist, int* __restrict__ gbase,
                       int* __restrict__ gcur, int L) {
    __shared__ int ssum[TPB];
    int t = threadIdx.x;
    int CH = (L + TPB - 1) / TPB;
    int lo = t * CH, hi = min(L, lo + CH);
    int s = 0;
    for (int i = lo; i < hi; i++) s += ghist[i];
    ssum[t] = s;
    __syncthreads();
    for (int off = 1; off < TPB; off <<= 1) {
        int v = (t >= off) ? ssum[t - off] : 0;
        __syncthreads();
        ssum[t] += v;
        __syncthreads();
    }
    int base = (t == 0) ? 0 : ssum[t - 1];
    for (int i = lo; i < hi; i++) { gbase[i] = base; gcur[i] = base; base += ghist[i]; }
    if (t == TPB - 1) gbase[L] = base;            // = E
}

// place (src,dst) pairs into range-sorted gbuf; per-block reservation + LDS cursors
__global__ void k_place(const int* __restrict__ ei, int* __restrict__ gcur,
                        uint2* __restrict__ gbuf, int E, int C) {
    __shared__ int h[MAXC];
    int t = threadIdx.x, b = blockIdx.x, j = b & 7;
    for (int c = t; c < C; c += TPB) h[c] = 0;
    __syncthreads();
    int base = b * EPB;
#pragma unroll
    for (int it = 0; it < EPB / TPB; it++) {      // pass 1: count
        int e = base + it * TPB + t;
        if (e < E) atomicAdd(&h[ei[E + e] >> RSH], 1);
    }
    __syncthreads();
    for (int c = t; c < C; c += TPB) {            // reserve global space per (c, shard)
        int v = h[c];
        if (v) h[c] = atomicAdd(&gcur[c * 8 + j], v);
    }
    __syncthreads();
#pragma unroll
    for (int it = 0; it < EPB / TPB; it++) {      // pass 2: place via LDS cursors
        int e = base + it * TPB + t;
        if (e < E) {
            int s = ei[e], d = ei[E + e];
            int pos = atomicAdd(&h[d >> RSH], 1);
            gbuf[pos] = make_uint2((unsigned)s, (unsigned)d);
        }
    }
}

// per-range degree histogram -> dinv
__global__ void k_degdinv(const uint2* __restrict__ gbuf, const int* __restrict__ gbase,
                          float* __restrict__ dinv, int N) {
    __shared__ int cnt[RNG];
    int t = threadIdx.x, r = blockIdx.x;
    if (t < RNG) cnt[t] = 0;
    __syncthreads();
    int lo = gbase[r * 8], hi = gbase[r * 8 + 8];
    for (int i = lo + t; i < hi; i += TPB)
        atomicAdd(&cnt[gbuf[i].y & (RNG - 1)], 1);
    __syncthreads();
    if (t < RNG) {
        int n = r * RNG + t;
        if (n < N) dinv[n] = rsqrtf((float)cnt[t] + 1.0f);   // +1 self-loop
    }
}

__global__ void k_hsx(const float* __restrict__ x, const float* __restrict__ dinv,
                      float* __restrict__ hsx, int N) {
    int gid = blockIdx.x * TPB + threadIdx.x;     // gid = n*16 + k
    if (gid >= N * 16) return;
    hsx[gid] = dinv[gid >> 4] * x[gid];
}

// range-owning LDS accumulation, F=16: 16 edge strands/block, unroll 2
__global__ void k_agg16(const uint2* __restrict__ gbuf, const int* __restrict__ gbase,
                        const float* __restrict__ hsx, float* __restrict__ agg, int N) {
    __shared__ float acc[RNG * 16];               // 8 KiB
    int t = threadIdx.x, r = blockIdx.x;
#pragma unroll
    for (int it = 0; it < (RNG * 16) / TPB; it++) {   // init with self-loop rows
        int idx = it * TPB + t;
        int n = r * RNG + (idx >> 4);
        acc[idx] = (n < N) ? hsx[(size_t)r * RNG * 16 + idx] : 0.f;
    }
    __syncthreads();
    int lo = gbase[r * 8], hi = gbase[r * 8 + 8];
    int f = t & 15;
    int i = lo + (t >> 4);                        // strand 0..15
    for (; i + 16 < hi; i += 32) {
        uint2 p0 = gbuf[i];
        uint2 p1 = gbuf[i + 16];
        float v0 = hsx[p0.x * 16 + f];
        float v1 = hsx[p1.x * 16 + f];
        atomicAdd(&acc[(p0.y & (RNG - 1)) * 16 + f], v0);
        atomicAdd(&acc[(p1.y & (RNG - 1)) * 16 + f], v1);
    }
    if (i < hi) {
        uint2 p = gbuf[i];
        atomicAdd(&acc[(p.y & (RNG - 1)) * 16 + f], hsx[p.x * 16 + f]);
    }
    __syncthreads();
#pragma unroll
    for (int it = 0; it < (RNG * 16) / TPB; it++) {
        int idx = it * TPB + t;
        int n = r * RNG + (idx >> 4);
        if (n < N) agg[(size_t)r * RNG * 16 + idx] = acc[idx];
    }
}

// hs1[n][j] = dinv * relu(dinv * (agg16[n] . W1[:,j]) + b1[j])
__global__ void k_gemm1(const float* __restrict__ agg, const float* __restrict__ W1,
                        const float* __restrict__ b1, const float* __restrict__ dinv,
                        float* __restrict__ hs1, int N) {
    __shared__ float w[16 * 64];
    __shared__ float sb[64];
    for (int i = threadIdx.x; i < 16 * 64; i += TPB) w[i] = W1[i];
    if (threadIdx.x < 64) sb[threadIdx.x] = b1[threadIdx.x];
    __syncthreads();
    int gid = blockIdx.x * TPB + threadIdx.x;     // gid = n*64 + j
    int n = gid >> 6, j = gid & 63;
    if (n >= N) return;
    const float* ar = agg + n * 16;               // wave-uniform row
    float s = 0.f;
#pragma unroll
    for (int k = 0; k < 16; k++) s += ar[k] * w[k * 64 + j];
    float dn = dinv[n];
    float v = dn * s + sb[j];
    v = v > 0.f ? v : 0.f;
    hs1[gid] = v * dn;
}

// range-owning LDS accumulation, F=64: wave per edge, unroll 4
__global__ void k_agg64(const uint2* __restrict__ gbuf, const int* __restrict__ gbase,
                        const float* __restrict__ hs1, float* __restrict__ acc1, int N) {
    __shared__ float acc[RNG * 64];               // 32 KiB
    int t = threadIdx.x, r = blockIdx.x;
#pragma unroll
    for (int it = 0; it < (RNG * 64) / TPB; it++) {   // init with self-loop rows
        int idx = it * TPB + t;
        int n = r * RNG + (idx >> 6);
        acc[idx] = (n < N) ? hs1[(size_t)r * RNG * 64 + idx] : 0.f;
    }
    __syncthreads();
    int lo = gbase[r * 8], hi = gbase[r * 8 + 8];
    int l = t & 63;
    int i = lo + (t >> 6);                        // wave strand 0..3
    for (; i + 12 < hi; i += 16) {
        uint2 p0 = gbuf[i], p1 = gbuf[i + 4], p2 = gbuf[i + 8], p3 = gbuf[i + 12];
        float v0 = hs1[p0.x * 64 + l];
        float v1 = hs1[p1.x * 64 + l];
        float v2 = hs1[p2.x * 64 + l];
        float v3 = hs1[p3.x * 64 + l];
        atomicAdd(&acc[(p0.y & (RNG - 1)) * 64 + l], v0);
        atomicAdd(&acc[(p1.y & (RNG - 1)) * 64 + l], v1);
        atomicAdd(&acc[(p2.y & (RNG - 1)) * 64 + l], v2);
        atomicAdd(&acc[(p3.y & (RNG - 1)) * 64 + l], v3);
    }
    for (; i < hi; i += 4) {
        uint2 p = gbuf[i];
        atomicAdd(&acc[(p.y & (RNG - 1)) * 64 + l], hs1[p.x * 64 + l]);
    }
    __syncthreads();
#pragma unroll
    for (int it = 0; it < (RNG * 64) / TPB; it++) {
        int idx = it * TPB + t;
        int n = r * RNG + (idx >> 6);
        if (n < N) acc1[(size_t)r * RNG * 64 + idx] = acc[idx];
    }
}

// out[n][o] = dinv[n] * (acc1[n] . Wf[:,o]) + bf[o]
__global__ void k_out(const float* __restrict__ acc1, const float* __restrict__ dinv,
                      const float* __restrict__ Wf, const float* __restrict__ bf,
                      float* __restrict__ out, int N) {
    __shared__ float wf[64 * 16];
    __shared__ float sbf[16];
    int t = threadIdx.x;
    for (int i = t; i < 64 * 16; i += TPB) wf[i] = Wf[i];
    if (t < 16) sbf[t] = bf[t];
    __syncthreads();
    int gid = blockIdx.x * TPB + t;               // gid = n*16 + o
    int n = gid >> 4, o = gid & 15;
    if (n >= N) return;
    const float4* A = (const float4*)(acc1 + (size_t)n * 64);
    float s = 0.f;
#pragma unroll
    for (int q = 0; q < 16; q++) {
        float4 a = A[q];
        s += a.x * wf[(4 * q + 0) * 16 + o];
        s += a.y * wf[(4 * q + 1) * 16 + o];
        s += a.z * wf[(4 * q + 2) * 16 + o];
        s += a.w * wf[(4 * q + 3) * 16 + o];
    }
    out[gid] = dinv[n] * s + sbf[o];
}

extern "C" void kernel_launch(void* const* d_in, const int* in_sizes, int n_in,
                              void* d_out, int out_size, void* d_ws, size_t ws_size,
                              hipStream_t stream) {
    const float* x  = (const float*)d_in[0];
    const int*   ei = (const int*)d_in[1];
    const float* W1 = (const float*)d_in[2];
    const float* b1 = (const float*)d_in[3];
    const float* W2 = (const float*)d_in[4];
    const float* b2 = (const float*)d_in[5];
    const float* WL = (const float*)d_in[6];
    const float* bL = (const float*)d_in[7];
    float* out = (float*)d_out;

    const int N  = in_sizes[0] / 16;   // 100000
    const int E  = in_sizes[1] / 2;    // 1600000
    const int NR = (N + RNG - 1) >> RSH;   // 782 ranges
    const int C  = NR;
    const int L  = C * 8;                  // (range, shard) cells
    const int NB = (E + EPB - 1) / EPB;    // hist/place blocks

    // ws: gbuf[E] uint2 | ghist[L] | gbase[L+1] | gcur[L] | (pad) |
    //     dinv[N] hsx[16N] agg16[16N] hs1[64N] acc1[64N] Wf[1024] bf[16]
    int* wsi    = (int*)d_ws;
    uint2* gbuf = (uint2*)wsi;
    int* ghist  = wsi + (size_t)2 * E;
    int* gbase  = ghist + L;
    int* gcur   = gbase + L + 1;
    size_t itot = (size_t)2 * E + 3 * (size_t)L + 1;
    itot = (itot + 3) & ~(size_t)3;                 // 16B-align float section
    float* dinv  = (float*)(wsi + itot);
    float* hsx   = dinv + N;
    float* agg16 = hsx + (size_t)N * 16;
    float* hs1   = agg16 + (size_t)N * 16;
    float* acc1  = hs1 + (size_t)N * 64;
    float* Wf    = acc1 + (size_t)N * 64;
    float* bf    = Wf + 64 * 16;

    // weight fusion (independent — overlaps the sort build)
    k_wfuse<<<4, TPB, 0, stream>>>(W2, WL, b2, bL, Wf, bf);

    // ---- counting sort of edges by dst-range (XCD-sharded) ----
    hipMemsetAsync(ghist, 0, (size_t)L * 4, stream);
    k_hist<<<NB, TPB, 0, stream>>>(ei, ghist, E, C);
    k_scan<<<1, TPB, 0, stream>>>(ghist, gbase, gcur, L);
    k_place<<<NB, TPB, 0, stream>>>(ei, gcur, gbuf, E, C);
    k_degdinv<<<NR, TPB, 0, stream>>>(gbuf, gbase, dinv, N);

    // ---- layer 1 aggregation at F=16 ----
    k_hsx<<<((size_t)N * 16 + TPB - 1) / TPB, TPB, 0, stream>>>(x, dinv, hsx, N);
    k_agg16<<<NR, TPB, 0, stream>>>(gbuf, gbase, hsx, agg16, N);

    // ---- GEMM 16->64 + relu + pre-scale ----
    k_gemm1<<<((size_t)N * 64 + TPB - 1) / TPB, TPB, 0, stream>>>(agg16, W1, b1, dinv, hs1, N);

    // ---- layer 2 aggregation at F=64 ----
    k_agg64<<<NR, TPB, 0, stream>>>(gbuf, gbase, hs1, acc1, N);

    // ---- fused conv2 + readout ----
    k_out<<<((size_t)N * 16 + TPB - 1) / TPB, TPB, 0, stream>>>(acc1, dinv, Wf, bf, out, N);
}

// Round 6
// 354.227 us; speedup vs baseline: 3.0645x; 3.0645x over previous
//
#include <hip/hip_runtime.h>

#define TPB 256
#define RNG 128          // nodes per range
#define RSH 7            // log2(RNG)
#define MAXC 1024        // max ranges supported by LDS hist (N <= 131072)
#define EPB 2048         // edges per block in hist/place

// ---------------------------------------------------------------------------
// GCN via (A_norm)(h W) = (A_norm h) W.
// Build: 2-phase counting sort -> per-node CSR (start[] rowptr + bucketS[] src)
//   A: histogram by dst-range (XCD-sharded cells) -> scan -> chunked place
//   B: per-range LDS sort -> node-sorted bucketS, start, dinv (dense writes)
// Aggregate: wave-per-node gathers with many independent load chains.
//   hsx  = dinv * x                              [N,16]
//   agg16[d] = hsx[d] + sum_{s->d} hsx[s]
//   hs1  = dinv * relu(dinv * agg16 @ W1 + b1)   [N,64]
//   acc1[d] = hs1[d] + sum_{s->d} hs1[s]
//   out  = dinv*acc1 @ (W2@WL) + (b2@WL + bL)
// ---------------------------------------------------------------------------

// Wf[k][o] = sum_j W2[k][j]*WL[j][o]; bf[o] = sum_j b2[j]*WL[j][o] + bL[o]
__global__ void k_wfuse(const float* __restrict__ W2, const float* __restrict__ WL,
                        const float* __restrict__ b2, const float* __restrict__ bL,
                        float* __restrict__ Wf, float* __restrict__ bf) {
    int gid = blockIdx.x * TPB + threadIdx.x;     // 4 blocks * 256 = 1024 = 64*16
    int k = gid >> 4, o = gid & 15;
    if (k < 64) {
        float s = 0.f;
#pragma unroll 8
        for (int j = 0; j < 128; j++) s += W2[k * 128 + j] * WL[j * 16 + o];
        Wf[gid] = s;
    }
    if (gid < 16) {
        float s = bL[gid];
        for (int j = 0; j < 128; j++) s += b2[j] * WL[j * 16 + gid];
        bf[gid] = s;
    }
}

// per-block LDS histogram of dst-range, merged into ghist[c*8 + shard]
__global__ void k_hist(const int* __restrict__ ei, int* __restrict__ ghist,
                       int E, int C) {
    __shared__ int h[MAXC];
    int t = threadIdx.x, b = blockIdx.x, j = b & 7;
    for (int c = t; c < C; c += TPB) h[c] = 0;
    __syncthreads();
    int base = b * EPB;
#pragma unroll
    for (int it = 0; it < EPB / TPB; it++) {
        int e = base + it * TPB + t;
        if (e < E) atomicAdd(&h[ei[E + e] >> RSH], 1);
    }
    __syncthreads();
    for (int c = t; c < C; c += TPB) {
        int v = h[c];
        if (v) atomicAdd(&ghist[c * 8 + j], v);
    }
}

// single-block exclusive scan of ghist[0..L) -> gbase (+sentinel), gcur copy
__global__ void k_scan(const int* __restrict__ ghist, int* __restrict__ gbase,
                       int* __restrict__ gcur, int L) {
    __shared__ int ssum[TPB];
    int t = threadIdx.x;
    int CH = (L + TPB - 1) / TPB;
    int lo = t * CH, hi = min(L, lo + CH);
    int s = 0;
    for (int i = lo; i < hi; i++) s += ghist[i];
    ssum[t] = s;
    __syncthreads();
    for (int off = 1; off < TPB; off <<= 1) {
        int v = (t >= off) ? ssum[t - off] : 0;
        __syncthreads();
        ssum[t] += v;
        __syncthreads();
    }
    int base = (t == 0) ? 0 : ssum[t - 1];
    for (int i = lo; i < hi; i++) { gbase[i] = base; gcur[i] = base; base += ghist[i]; }
    if (t == TPB - 1) gbase[L] = base;            // = E
}

// place (src,dst) pairs into range-sorted gbuf; per-block chunk reservation
__global__ void k_place(const int* __restrict__ ei, int* __restrict__ gcur,
                        uint2* __restrict__ gbuf, int E, int C) {
    __shared__ int h[MAXC];
    int t = threadIdx.x, b = blockIdx.x, j = b & 7;
    for (int c = t; c < C; c += TPB) h[c] = 0;
    __syncthreads();
    int base = b * EPB;
#pragma unroll
    for (int it = 0; it < EPB / TPB; it++) {      // pass 1: count
        int e = base + it * TPB + t;
        if (e < E) atomicAdd(&h[ei[E + e] >> RSH], 1);
    }
    __syncthreads();
    for (int c = t; c < C; c += TPB) {            // reserve chunk per (c, shard)
        int v = h[c];
        if (v) h[c] = atomicAdd(&gcur[c * 8 + j], v);
    }
    __syncthreads();
#pragma unroll
    for (int it = 0; it < EPB / TPB; it++) {      // pass 2: place via LDS cursors
        int e = base + it * TPB + t;
        if (e < E) {
            int s = ei[e], d = ei[E + e];
            int pos = atomicAdd(&h[d >> RSH], 1);
            gbuf[pos] = make_uint2((unsigned)s, (unsigned)d);
        }
    }
}

// per-range node-sort: gbuf pairs -> bucketS (src only, node-sorted), start, dinv
__global__ void k_sort2(const uint2* __restrict__ gbuf, const int* __restrict__ gbase,
                        int* __restrict__ bucketS, int* __restrict__ start,
                        float* __restrict__ dinv, int N, int E) {
    __shared__ int cnt[RNG];
    __shared__ int offs[RNG];
    __shared__ int cur[RNG];
    int t = threadIdx.x, r = blockIdx.x;
    if (t < RNG) cnt[t] = 0;
    __syncthreads();
    int lo = gbase[r * 8], hi = gbase[r * 8 + 8];
    for (int i = lo + t; i < hi; i += TPB)
        atomicAdd(&cnt[gbuf[i].y & (RNG - 1)], 1);
    __syncthreads();
    if (t < RNG) offs[t] = cnt[t];
    __syncthreads();
    for (int off = 1; off < RNG; off <<= 1) {     // Hillis-Steele inclusive scan
        int v = 0;
        if (t < RNG && t >= off) v = offs[t - off];
        __syncthreads();
        if (t < RNG) offs[t] += v;
        __syncthreads();
    }
    if (t < RNG) {
        int ex = offs[t] - cnt[t];                // exclusive
        cur[t] = ex;
        int n = r * RNG + t;
        if (n < N) {
            start[n] = lo + ex;
            dinv[n] = rsqrtf((float)cnt[t] + 1.0f);   // +1 self-loop
        }
    }
    if (r == 0 && t == 0) start[N] = E;           // CSR sentinel
    __syncthreads();
    for (int i = lo + t; i < hi; i += TPB) {
        uint2 p = gbuf[i];
        int pos = lo + atomicAdd(&cur[p.y & (RNG - 1)], 1);
        bucketS[pos] = (int)p.x;                  // dense within [lo,hi)
    }
}

__global__ void k_hsx(const float* __restrict__ x, const float* __restrict__ dinv,
                      float* __restrict__ hsx, int N) {
    int gid = blockIdx.x * TPB + threadIdx.x;     // gid = n*16 + k
    if (gid >= N * 16) return;
    hsx[gid] = dinv[gid >> 4] * x[gid];
}

// wave per node; lane = g*4 + q: g in [0,16) edge strand, q in [0,4) float4 slot
__global__ void k_gather16(const int* __restrict__ bucket, const int* __restrict__ start,
                           const float4* __restrict__ hsx, float4* __restrict__ agg, int N) {
    int n = (blockIdx.x * TPB + threadIdx.x) >> 6;
    if (n >= N) return;
    int lane = threadIdx.x & 63;
    int g = lane >> 2, q = lane & 3;
    int base = start[n], d = start[n + 1] - base;
    float4 sum = make_float4(0.f, 0.f, 0.f, 0.f);
    if (g == 0) sum = hsx[n * 4 + q];             // self-loop
    for (int k = g; k < d; k += 16) {
        int s = bucket[base + k];
        float4 v = hsx[s * 4 + q];
        sum.x += v.x; sum.y += v.y; sum.z += v.z; sum.w += v.w;
    }
#pragma unroll
    for (int m = 4; m <= 32; m <<= 1) {
        sum.x += __shfl_xor(sum.x, m);
        sum.y += __shfl_xor(sum.y, m);
        sum.z += __shfl_xor(sum.z, m);
        sum.w += __shfl_xor(sum.w, m);
    }
    if (g == 0) agg[n * 4 + q] = sum;
}

// hs1[n][j] = dinv * relu(dinv * (agg16[n] . W1[:,j]) + b1[j])
__global__ void k_gemm1(const float* __restrict__ agg, const float* __restrict__ W1,
                        const float* __restrict__ b1, const float* __restrict__ dinv,
                        float* __restrict__ hs1, int N) {
    __shared__ float w[16 * 64];
    __shared__ float sb[64];
    for (int i = threadIdx.x; i < 16 * 64; i += TPB) w[i] = W1[i];
    if (threadIdx.x < 64) sb[threadIdx.x] = b1[threadIdx.x];
    __syncthreads();
    int gid = blockIdx.x * TPB + threadIdx.x;     // gid = n*64 + j
    int n = gid >> 6, j = gid & 63;
    if (n >= N) return;
    const float* ar = agg + n * 16;               // wave-uniform row
    float s = 0.f;
#pragma unroll
    for (int k = 0; k < 16; k++) s += ar[k] * w[k * 64 + j];
    float dn = dinv[n];
    float v = dn * s + sb[j];
    v = v > 0.f ? v : 0.f;
    hs1[gid] = v * dn;
}

// wave per node; lane = g*16 + q: g in [0,4) strand, q in [0,16) float4 slot.
// 4x unroll -> 16 independent bucket->row chains per wave.
__global__ void k_gather64(const int* __restrict__ bucket, const int* __restrict__ start,
                           const float4* __restrict__ hs1, float4* __restrict__ acc, int N) {
    int n = (blockIdx.x * TPB + threadIdx.x) >> 6;
    if (n >= N) return;
    int lane = threadIdx.x & 63;
    int g = lane >> 4, q = lane & 15;
    int base = start[n], d = start[n + 1] - base;
    float4 sum = make_float4(0.f, 0.f, 0.f, 0.f);
    if (g == 0) sum = hs1[n * 16 + q];            // self-loop
    int k = g;
    for (; k + 12 < d; k += 16) {
        int s0 = bucket[base + k];
        int s1 = bucket[base + k + 4];
        int s2 = bucket[base + k + 8];
        int s3 = bucket[base + k + 12];
        float4 v0 = hs1[s0 * 16 + q];
        float4 v1 = hs1[s1 * 16 + q];
        float4 v2 = hs1[s2 * 16 + q];
        float4 v3 = hs1[s3 * 16 + q];
        sum.x += v0.x + v1.x + v2.x + v3.x;
        sum.y += v0.y + v1.y + v2.y + v3.y;
        sum.z += v0.z + v1.z + v2.z + v3.z;
        sum.w += v0.w + v1.w + v2.w + v3.w;
    }
    for (; k < d; k += 4) {
        int s = bucket[base + k];
        float4 v = hs1[s * 16 + q];
        sum.x += v.x; sum.y += v.y; sum.z += v.z; sum.w += v.w;
    }
#pragma unroll
    for (int m = 16; m <= 32; m <<= 1) {
        sum.x += __shfl_xor(sum.x, m);
        sum.y += __shfl_xor(sum.y, m);
        sum.z += __shfl_xor(sum.z, m);
        sum.w += __shfl_xor(sum.w, m);
    }
    if (g == 0) acc[n * 16 + q] = sum;
}

// out[n][o] = dinv[n] * (acc1[n] . Wf[:,o]) + bf[o]
__global__ void k_out(const float* __restrict__ acc1, const float* __restrict__ dinv,
                      const float* __restrict__ Wf, const float* __restrict__ bf,
                      float* __restrict__ out, int N) {
    __shared__ float wf[64 * 16];
    __shared__ float sbf[16];
    int t = threadIdx.x;
    for (int i = t; i < 64 * 16; i += TPB) wf[i] = Wf[i];
    if (t < 16) sbf[t] = bf[t];
    __syncthreads();
    int gid = blockIdx.x * TPB + t;               // gid = n*16 + o
    int n = gid >> 4, o = gid & 15;
    if (n >= N) return;
    const float4* A = (const float4*)(acc1 + (size_t)n * 64);
    float s = 0.f;
#pragma unroll
    for (int q = 0; q < 16; q++) {
        float4 a = A[q];
        s += a.x * wf[(4 * q + 0) * 16 + o];
        s += a.y * wf[(4 * q + 1) * 16 + o];
        s += a.z * wf[(4 * q + 2) * 16 + o];
        s += a.w * wf[(4 * q + 3) * 16 + o];
    }
    out[gid] = dinv[n] * s + sbf[o];
}

extern "C" void kernel_launch(void* const* d_in, const int* in_sizes, int n_in,
                              void* d_out, int out_size, void* d_ws, size_t ws_size,
                              hipStream_t stream) {
    const float* x  = (const float*)d_in[0];
    const int*   ei = (const int*)d_in[1];
    const float* W1 = (const float*)d_in[2];
    const float* b1 = (const float*)d_in[3];
    const float* W2 = (const float*)d_in[4];
    const float* b2 = (const float*)d_in[5];
    const float* WL = (const float*)d_in[6];
    const float* bL = (const float*)d_in[7];
    float* out = (float*)d_out;

    const int N  = in_sizes[0] / 16;       // 100000
    const int E  = in_sizes[1] / 2;        // 1600000
    const int C  = (N + RNG - 1) >> RSH;   // 782 ranges
    const int L  = C * 8;                  // (range, shard) cells
    const int NB = (E + EPB - 1) / EPB;    // hist/place blocks

    // ws: gbuf[E] uint2 | bucketS[E] | ghist[L] | gbase[L+1] | gcur[L] | start[N+1] | pad |
    //     dinv[N] hsx[16N] agg16[16N] hs1[64N] acc1[64N] Wf[1024] bf[16]
    int* wsi      = (int*)d_ws;
    uint2* gbuf   = (uint2*)wsi;                  // 8B-aligned at ws start
    int* bucketS  = wsi + (size_t)2 * E;
    int* ghist    = bucketS + E;
    int* gbase    = ghist + L;
    int* gcur     = gbase + L + 1;
    int* start    = gcur + L;
    size_t itot   = (size_t)3 * E + 3 * (size_t)L + 1 + (N + 1);
    itot = (itot + 3) & ~(size_t)3;               // 16B-align float section
    float* dinv  = (float*)(wsi + itot);
    float* hsx   = dinv + N;
    float* agg16 = hsx + (size_t)N * 16;
    float* hs1   = agg16 + (size_t)N * 16;
    float* acc1  = hs1 + (size_t)N * 64;
    float* Wf    = acc1 + (size_t)N * 64;
    float* bf    = Wf + 64 * 16;

    // weight fusion (independent — overlaps the sort build)
    k_wfuse<<<4, TPB, 0, stream>>>(W2, WL, b2, bL, Wf, bf);

    // ---- phase A: counting sort by dst-range (XCD-sharded cells) ----
    hipMemsetAsync(ghist, 0, (size_t)L * 4, stream);
    k_hist<<<NB, TPB, 0, stream>>>(ei, ghist, E, C);
    k_scan<<<1, TPB, 0, stream>>>(ghist, gbase, gcur, L);
    k_place<<<NB, TPB, 0, stream>>>(ei, gcur, gbuf, E, C);

    // ---- phase B: per-range node sort -> CSR (start, bucketS, dinv) ----
    k_sort2<<<C, TPB, 0, stream>>>(gbuf, gbase, bucketS, start, dinv, N, E);

    // ---- layer 1 aggregation at F=16 ----
    k_hsx<<<((size_t)N * 16 + TPB - 1) / TPB, TPB, 0, stream>>>(x, dinv, hsx, N);
    k_gather16<<<((size_t)N * 64 + TPB - 1) / TPB, TPB, 0, stream>>>(
        bucketS, start, (const float4*)hsx, (float4*)agg16, N);

    // ---- GEMM 16->64 + relu + pre-scale ----
    k_gemm1<<<((size_t)N * 64 + TPB - 1) / TPB, TPB, 0, stream>>>(agg16, W1, b1, dinv, hs1, N);

    // ---- layer 2 aggregation at F=64 ----
    k_gather64<<<((size_t)N * 64 + TPB - 1) / TPB, TPB, 0, stream>>>(
        bucketS, start, (const float4*)hs1, (float4*)acc1, N);

    // ---- fused conv2 + readout ----
    k_out<<<((size_t)N * 16 + TPB - 1) / TPB, TPB, 0, stream>>>(acc1, dinv, Wf, bf, out, N);
}

// Round 7
// 332.882 us; speedup vs baseline: 3.2610x; 1.0641x over previous
//
#include <hip/hip_runtime.h>
#include <hip/hip_fp16.h>

#define TPB 256
#define RNG 128          // nodes per range
#define RSH 7            // log2(RNG)
#define MAXC 1024        // max ranges supported by LDS hist (N <= 131072)
#define EPB 2048         // edges per block in hist/place

// ---------------------------------------------------------------------------
// GCN via (A_norm)(h W) = (A_norm h) W.
// Build: 2-phase counting sort -> per-node CSR (start[] rowptr + bucketS[] src)
//   A: histogram by dst-range (XCD-sharded cells) -> scan -> chunked place
//      (pairs packed: src<<7 | dst&127)
//   B: per-range LDS sort -> bucketS, start, dinv; fused hsx = fp16(dinv*x)
// Features stored fp16 (accumulate fp32): hsx [N,16] 32B rows, hs1 [N,64] 128B.
// k_l1: wave/node gather16 (32 strands) + LDS round-trip + 16->64 GEMM+relu.
// k_l2: wave/node gather64 (16 chains) + in-wave 64->16 dot (Wf = W2@WL).
// ---------------------------------------------------------------------------

__device__ inline void acc8(float a[8], uint4 u) {
    const __half2* h = (const __half2*)&u;
#pragma unroll
    for (int i = 0; i < 4; i++) {
        float2 f = __half22float2(h[i]);
        a[2 * i]     += f.x;
        a[2 * i + 1] += f.y;
    }
}

// Wf[k][o] = sum_j W2[k][j]*WL[j][o]; bf[o] = sum_j b2[j]*WL[j][o] + bL[o]
__global__ void k_wfuse(const float* __restrict__ W2, const float* __restrict__ WL,
                        const float* __restrict__ b2, const float* __restrict__ bL,
                        float* __restrict__ Wf, float* __restrict__ bf) {
    int gid = blockIdx.x * TPB + threadIdx.x;     // 4 blocks * 256 = 1024 = 64*16
    int k = gid >> 4, o = gid & 15;
    if (k < 64) {
        float s = 0.f;
#pragma unroll 8
        for (int j = 0; j < 128; j++) s += W2[k * 128 + j] * WL[j * 16 + o];
        Wf[gid] = s;
    }
    if (gid < 16) {
        float s = bL[gid];
        for (int j = 0; j < 128; j++) s += b2[j] * WL[j * 16 + gid];
        bf[gid] = s;
    }
}

// per-block LDS histogram of dst-range, merged into ghist[c*8 + shard]
__global__ void k_hist(const int* __restrict__ ei, int* __restrict__ ghist,
                       int E, int C) {
    __shared__ int h[MAXC];
    int t = threadIdx.x, b = blockIdx.x, j = b & 7;
    for (int c = t; c < C; c += TPB) h[c] = 0;
    __syncthreads();
    int base = b * EPB;
#pragma unroll
    for (int it = 0; it < EPB / TPB; it++) {
        int e = base + it * TPB + t;
        if (e < E) atomicAdd(&h[ei[E + e] >> RSH], 1);
    }
    __syncthreads();
    for (int c = t; c < C; c += TPB) {
        int v = h[c];
        if (v) atomicAdd(&ghist[c * 8 + j], v);
    }
}

// single-block exclusive scan of ghist[0..L) -> gbase (+sentinel), gcur copy
__global__ void k_scan(const int* __restrict__ ghist, int* __restrict__ gbase,
                       int* __restrict__ gcur, int L) {
    __shared__ int ssum[TPB];
    int t = threadIdx.x;
    int CH = (L + TPB - 1) / TPB;
    int lo = t * CH, hi = min(L, lo + CH);
    int s = 0;
    for (int i = lo; i < hi; i++) s += ghist[i];
    ssum[t] = s;
    __syncthreads();
    for (int off = 1; off < TPB; off <<= 1) {
        int v = (t >= off) ? ssum[t - off] : 0;
        __syncthreads();
        ssum[t] += v;
        __syncthreads();
    }
    int base = (t == 0) ? 0 : ssum[t - 1];
    for (int i = lo; i < hi; i++) { gbase[i] = base; gcur[i] = base; base += ghist[i]; }
    if (t == TPB - 1) gbase[L] = base;            // = E
}

// place packed (src<<7 | dst&127) into range-sorted gbuf; chunk reservation
__global__ void k_place(const int* __restrict__ ei, int* __restrict__ gcur,
                        unsigned* __restrict__ gbuf, int E, int C) {
    __shared__ int h[MAXC];
    int t = threadIdx.x, b = blockIdx.x, j = b & 7;
    for (int c = t; c < C; c += TPB) h[c] = 0;
    __syncthreads();
    int base = b * EPB;
#pragma unroll
    for (int it = 0; it < EPB / TPB; it++) {      // pass 1: count
        int e = base + it * TPB + t;
        if (e < E) atomicAdd(&h[ei[E + e] >> RSH], 1);
    }
    __syncthreads();
    for (int c = t; c < C; c += TPB) {            // reserve chunk per (c, shard)
        int v = h[c];
        if (v) h[c] = atomicAdd(&gcur[c * 8 + j], v);
    }
    __syncthreads();
#pragma unroll
    for (int it = 0; it < EPB / TPB; it++) {      // pass 2: place via LDS cursors
        int e = base + it * TPB + t;
        if (e < E) {
            int s = ei[e], d = ei[E + e];
            int pos = atomicAdd(&h[d >> RSH], 1);
            gbuf[pos] = ((unsigned)s << RSH) | (unsigned)(d & (RNG - 1));
        }
    }
}

// per-range node-sort -> bucketS/start/dinv; fused hsx = fp16(dinv*x)
__global__ void k_sort2(const unsigned* __restrict__ gbuf, const int* __restrict__ gbase,
                        const float* __restrict__ x,
                        int* __restrict__ bucketS, int* __restrict__ start,
                        float* __restrict__ dinv, __half2* __restrict__ hsx,
                        int N, int E) {
    __shared__ int cnt[RNG];
    __shared__ int offs[RNG];
    __shared__ int cur[RNG];
    __shared__ float sdi[RNG];
    int t = threadIdx.x, r = blockIdx.x;
    if (t < RNG) cnt[t] = 0;
    __syncthreads();
    int lo = gbase[r * 8], hi = gbase[r * 8 + 8];
    for (int i = lo + t; i < hi; i += TPB)
        atomicAdd(&cnt[gbuf[i] & (RNG - 1)], 1);
    __syncthreads();
    if (t < RNG) offs[t] = cnt[t];
    __syncthreads();
    for (int off = 1; off < RNG; off <<= 1) {     // Hillis-Steele inclusive scan
        int v = 0;
        if (t < RNG && t >= off) v = offs[t - off];
        __syncthreads();
        if (t < RNG) offs[t] += v;
        __syncthreads();
    }
    if (t < RNG) {
        int ex = offs[t] - cnt[t];                // exclusive
        cur[t] = ex;
        float di = rsqrtf((float)cnt[t] + 1.0f);  // +1 self-loop
        sdi[t] = di;
        int n = r * RNG + t;
        if (n < N) { start[n] = lo + ex; dinv[n] = di; }
    }
    if (r == 0 && t == 0) start[N] = E;           // CSR sentinel
    __syncthreads();
    for (int i = lo + t; i < hi; i += TPB) {
        unsigned p = gbuf[i];
        int pos = lo + atomicAdd(&cur[p & (RNG - 1)], 1);
        bucketS[pos] = (int)(p >> RSH);
    }
    // fused: hsx[n][:] = fp16(dinv[n] * x[n][:]) — 128 nodes x 8 half2
    for (int idx = t; idx < RNG * 8; idx += TPB) {
        int ln = idx >> 3, f2 = idx & 7;
        int n = r * RNG + ln;
        if (n < N) {
            float2 xv = ((const float2*)x)[(size_t)n * 8 + f2];
            float dn = sdi[ln];
            hsx[(size_t)n * 8 + f2] = __floats2half2_rn(xv.x * dn, xv.y * dn);
        }
    }
}

// layer 1: wave/node. gather16 (32 strands, fp16 rows) + 16->64 GEMM + relu.
// hs1[n][j] = fp16( dinv * relu(dinv * (agg16[n] . W1[:,j]) + b1[j]) )
__global__ void k_l1(const int* __restrict__ bucketS, const int* __restrict__ start,
                     const uint4* __restrict__ hsx, const float* __restrict__ W1,
                     const float* __restrict__ b1, const float* __restrict__ dinv,
                     __half2* __restrict__ hs1, int N) {
    __shared__ float w1[16 * 64];
    __shared__ float sb1[64];
    __shared__ float aggrow[4][16];
    int t = threadIdx.x;
    for (int i = t; i < 16 * 64; i += TPB) w1[i] = W1[i];
    if (t < 64) sb1[t] = b1[t];
    __syncthreads();
    int wid = t >> 6, lane = t & 63;
    int n = blockIdx.x * 4 + wid;                 // wave-uniform
    if (n >= N) return;
    int g = lane >> 1, q = lane & 1;              // 32 strands x 2 slots (16B)
    int base = start[n], d = start[n + 1] - base;
    float a[8] = {0.f, 0.f, 0.f, 0.f, 0.f, 0.f, 0.f, 0.f};
    if (g == 0) acc8(a, hsx[(size_t)n * 2 + q]);  // self-loop
    for (int k = g; k < d; k += 32) {
        int s = bucketS[base + k];
        acc8(a, hsx[(size_t)s * 2 + q]);
    }
#pragma unroll
    for (int m = 2; m <= 32; m <<= 1)
#pragma unroll
        for (int i = 0; i < 8; i++) a[i] += __shfl_xor(a[i], m);
    if (g == 0) {
#pragma unroll
        for (int i = 0; i < 8; i++) aggrow[wid][q * 8 + i] = a[i];
    }
    // wave-coherent LDS round-trip (disjoint region per wave; in-order DS pipe)
    float dn = dinv[n];
    float s = 0.f;
#pragma unroll
    for (int k = 0; k < 16; k++) s += aggrow[wid][k] * w1[k * 64 + lane];
    float v = dn * s + sb1[lane];
    v = fmaxf(v, 0.f) * dn;
    float pv = __shfl(v, lane | 1);               // even lane grabs odd lane's value
    if (!(lane & 1)) hs1[(size_t)n * 32 + (lane >> 1)] = __floats2half2_rn(v, pv);
}

// layer 2 + readout: wave/node. gather64 (8 strands x unroll 2, fp16 rows),
// then out[n][o] = dinv[n]*(row . Wf[:,o]) + bf[o] in-wave.
__global__ void k_l2(const int* __restrict__ bucketS, const int* __restrict__ start,
                     const uint4* __restrict__ hs1, const float* __restrict__ Wf,
                     const float* __restrict__ bfv, const float* __restrict__ dinv,
                     float* __restrict__ out, int N) {
    __shared__ float wf[64 * 16];
    __shared__ float sbf[16];
    __shared__ float row[4][64];
    int t = threadIdx.x;
    for (int i = t; i < 64 * 16; i += TPB) wf[i] = Wf[i];
    if (t < 16) sbf[t] = bfv[t];
    __syncthreads();
    int wid = t >> 6, lane = t & 63;
    int n = blockIdx.x * 4 + wid;                 // wave-uniform
    if (n >= N) return;
    int g = lane >> 3, q = lane & 7;              // 8 strands x 8 slots (16B)
    int base = start[n], d = start[n + 1] - base;
    float a[8] = {0.f, 0.f, 0.f, 0.f, 0.f, 0.f, 0.f, 0.f};
    if (g == 0) acc8(a, hs1[(size_t)n * 8 + q]);  // self-loop
    int k = g;
    for (; k + 8 < d; k += 16) {                  // 2x unroll: 16 chains in flight
        int s0 = bucketS[base + k];
        int s1 = bucketS[base + k + 8];
        uint4 u0 = hs1[(size_t)s0 * 8 + q];
        uint4 u1 = hs1[(size_t)s1 * 8 + q];
        acc8(a, u0);
        acc8(a, u1);
    }
    if (k < d) acc8(a, hs1[(size_t)bucketS[base + k] * 8 + q]);
#pragma unroll
    for (int m = 8; m <= 32; m <<= 1)
#pragma unroll
        for (int i = 0; i < 8; i++) a[i] += __shfl_xor(a[i], m);
    if (g == 0) {
#pragma unroll
        for (int i = 0; i < 8; i++) row[wid][q * 8 + i] = a[i];
    }
    // wave-coherent LDS round-trip, then 64->16 dot: lane = part*16 + o
    float dn = dinv[n];
    int o = lane & 15, part = lane >> 4;
    float s = 0.f;
#pragma unroll
    for (int j = 0; j < 16; j++) s += row[wid][part * 16 + j] * wf[(part * 16 + j) * 16 + o];
    s += __shfl_xor(s, 16);
    s += __shfl_xor(s, 32);
    if (part == 0) out[(size_t)n * 16 + o] = dn * s + sbf[o];
}

extern "C" void kernel_launch(void* const* d_in, const int* in_sizes, int n_in,
                              void* d_out, int out_size, void* d_ws, size_t ws_size,
                              hipStream_t stream) {
    const float* x  = (const float*)d_in[0];
    const int*   ei = (const int*)d_in[1];
    const float* W1 = (const float*)d_in[2];
    const float* b1 = (const float*)d_in[3];
    const float* W2 = (const float*)d_in[4];
    const float* b2 = (const float*)d_in[5];
    const float* WL = (const float*)d_in[6];
    const float* bL = (const float*)d_in[7];
    float* out = (float*)d_out;

    const int N  = in_sizes[0] / 16;       // 100000
    const int E  = in_sizes[1] / 2;        // 1600000
    const int C  = (N + RNG - 1) >> RSH;   // 782 ranges
    const int L  = C * 8;                  // (range, shard) cells
    const int NB = (E + EPB - 1) / EPB;    // hist/place blocks

    // ws ints: gbuf[E] | bucketS[E] | ghist[L] | gbase[L+1] | gcur[L] | start[N+1] | pad
    //    then: dinv[N] f32 | Wf[1024] f32 | bf[16] f32 | pad16B | hsx[8N] half2 | hs1[32N] half2
    int* wsi        = (int*)d_ws;
    unsigned* gbuf  = (unsigned*)wsi;
    int* bucketS    = wsi + E;
    int* ghist      = bucketS + E;
    int* gbase      = ghist + L;
    int* gcur       = gbase + L + 1;
    int* start      = gcur + L;
    size_t off      = (size_t)2 * E + 3 * (size_t)L + 1 + (N + 1);
    off = (off + 3) & ~(size_t)3;
    float* dinv  = (float*)(wsi + off);
    float* Wf    = dinv + N;
    float* bf    = Wf + 1024;
    off = off + N + 1024 + 16;
    off = (off + 3) & ~(size_t)3;                 // 16B-align fp16 section
    __half2* hsx = (__half2*)(wsi + off);         // 8N half2
    __half2* hs1 = (__half2*)(wsi + off + (size_t)8 * N);   // 32N half2

    // weight fusion (independent — overlaps the sort build)
    k_wfuse<<<4, TPB, 0, stream>>>(W2, WL, b2, bL, Wf, bf);

    // ---- phase A: counting sort by dst-range (XCD-sharded cells) ----
    hipMemsetAsync(ghist, 0, (size_t)L * 4, stream);
    k_hist<<<NB, TPB, 0, stream>>>(ei, ghist, E, C);
    k_scan<<<1, TPB, 0, stream>>>(ghist, gbase, gcur, L);
    k_place<<<NB, TPB, 0, stream>>>(ei, gcur, gbuf, E, C);

    // ---- phase B: per-range node sort -> CSR + dinv + fp16 hsx ----
    k_sort2<<<C, TPB, 0, stream>>>(gbuf, gbase, x, bucketS, start, dinv, hsx, N, E);

    // ---- layer 1: gather16 + GEMM(16->64) + relu + scale -> fp16 hs1 ----
    const int NW = (N + 3) / 4;                   // 4 nodes (waves) per block
    k_l1<<<NW, TPB, 0, stream>>>(bucketS, start, (const uint4*)hsx, W1, b1, dinv, hs1, N);

    // ---- layer 2 + readout: gather64 + dot(64->16) ----
    k_l2<<<NW, TPB, 0, stream>>>(bucketS, start, (const uint4*)hs1, Wf, bf, dinv, out, N);
}

// Round 8
// 271.978 us; speedup vs baseline: 3.9912x; 1.2239x over previous
//
#include <hip/hip_runtime.h>
#include <hip/hip_fp16.h>

#define TPB 256
#define RNG 128          // nodes per range
#define RSH 7            // log2(RNG)
#define MAXC 1024        // max ranges supported by LDS hist (N <= 131072)
#define EPB 2048         // edges per block in hist/place

// ---------------------------------------------------------------------------
// GCN, fully commuted: aggregate always at the narrowest width (16).
//   hsx = fp16(dinv*x)                     [N,16]  (32B rows, L2-resident)
//   l1f: agg16 = hsx[n] + sum hsx[s];  h1 = relu(dinv*agg16@W1 + b1)
//        z = fp16((h1*dinv) @ Wf)          [N,16]  where Wf = W2@WL
//   l3:  out = dinv*(z[n] + sum z[s]) + bf          (bf = b2@WL + bL)
// Build: 2-phase counting sort -> per-node CSR (start[], bucketS[]):
//   A: LDS histogram by dst-range (XCD-sharded cells) -> scan -> chunked place
//   B: per-range LDS node sort; fused hsx conversion.
// Gathers: wave/node, 16 strands x 4 lanes x uint2(8B); fp32 accumulate.
// ---------------------------------------------------------------------------

__device__ inline void acc4(float a[4], uint2 u) {
    __half2 h0 = *(__half2*)&u.x, h1 = *(__half2*)&u.y;
    float2 f0 = __half22float2(h0), f1 = __half22float2(h1);
    a[0] += f0.x; a[1] += f0.y; a[2] += f1.x; a[3] += f1.y;
}

// Wf[k][o] = sum_j W2[k][j]*WL[j][o]; bf[o] = sum_j b2[j]*WL[j][o] + bL[o].
// Also zeros ghist (saves a memset dispatch).
__global__ void k_wfuse(const float* __restrict__ W2, const float* __restrict__ WL,
                        const float* __restrict__ b2, const float* __restrict__ bL,
                        float* __restrict__ Wf, float* __restrict__ bf,
                        int* __restrict__ ghist, int L) {
    int gid = blockIdx.x * TPB + threadIdx.x;     // 4 blocks * 256 = 1024 = 64*16
    for (int i = gid; i < L; i += 4 * TPB) ghist[i] = 0;
    int k = gid >> 4, o = gid & 15;
    if (k < 64) {
        float s = 0.f;
#pragma unroll 8
        for (int j = 0; j < 128; j++) s += W2[k * 128 + j] * WL[j * 16 + o];
        Wf[gid] = s;
    }
    if (gid < 16) {
        float s = bL[gid];
        for (int j = 0; j < 128; j++) s += b2[j] * WL[j * 16 + gid];
        bf[gid] = s;
    }
}

// per-block LDS histogram of dst-range, merged into ghist[c*8 + shard]
__global__ void k_hist(const int* __restrict__ ei, int* __restrict__ ghist,
                       int E, int C) {
    __shared__ int h[MAXC];
    int t = threadIdx.x, b = blockIdx.x, j = b & 7;
    for (int c = t; c < C; c += TPB) h[c] = 0;
    __syncthreads();
    int base = b * EPB;
#pragma unroll
    for (int it = 0; it < EPB / TPB; it++) {
        int e = base + it * TPB + t;
        if (e < E) atomicAdd(&h[ei[E + e] >> RSH], 1);
    }
    __syncthreads();
    for (int c = t; c < C; c += TPB) {
        int v = h[c];
        if (v) atomicAdd(&ghist[c * 8 + j], v);
    }
}

// single-block exclusive scan of ghist[0..L) -> gbase (+sentinel), gcur copy
__global__ void k_scan(const int* __restrict__ ghist, int* __restrict__ gbase,
                       int* __restrict__ gcur, int L) {
    __shared__ int ssum[TPB];
    int t = threadIdx.x;
    int CH = (L + TPB - 1) / TPB;
    int lo = t * CH, hi = min(L, lo + CH);
    int s = 0;
    for (int i = lo; i < hi; i++) s += ghist[i];
    ssum[t] = s;
    __syncthreads();
    for (int off = 1; off < TPB; off <<= 1) {
        int v = (t >= off) ? ssum[t - off] : 0;
        __syncthreads();
        ssum[t] += v;
        __syncthreads();
    }
    int base = (t == 0) ? 0 : ssum[t - 1];
    for (int i = lo; i < hi; i++) { gbase[i] = base; gcur[i] = base; base += ghist[i]; }
    if (t == TPB - 1) gbase[L] = base;            // = E
}

// place packed (src<<7 | dst&127) into range-sorted gbuf; chunk reservation
__global__ void k_place(const int* __restrict__ ei, int* __restrict__ gcur,
                        unsigned* __restrict__ gbuf, int E, int C) {
    __shared__ int h[MAXC];
    int t = threadIdx.x, b = blockIdx.x, j = b & 7;
    for (int c = t; c < C; c += TPB) h[c] = 0;
    __syncthreads();
    int base = b * EPB;
#pragma unroll
    for (int it = 0; it < EPB / TPB; it++) {      // pass 1: count
        int e = base + it * TPB + t;
        if (e < E) atomicAdd(&h[ei[E + e] >> RSH], 1);
    }
    __syncthreads();
    for (int c = t; c < C; c += TPB) {            // reserve chunk per (c, shard)
        int v = h[c];
        if (v) h[c] = atomicAdd(&gcur[c * 8 + j], v);
    }
    __syncthreads();
#pragma unroll
    for (int it = 0; it < EPB / TPB; it++) {      // pass 2: place via LDS cursors
        int e = base + it * TPB + t;
        if (e < E) {
            int s = ei[e], d = ei[E + e];
            int pos = atomicAdd(&h[d >> RSH], 1);
            gbuf[pos] = ((unsigned)s << RSH) | (unsigned)(d & (RNG - 1));
        }
    }
}

// per-range node-sort -> bucketS/start/dinv; fused hsx = fp16(dinv*x)
__global__ void k_sort2(const unsigned* __restrict__ gbuf, const int* __restrict__ gbase,
                        const float* __restrict__ x,
                        int* __restrict__ bucketS, int* __restrict__ start,
                        float* __restrict__ dinv, __half2* __restrict__ hsx,
                        int N, int E) {
    __shared__ int cnt[RNG];
    __shared__ int offs[RNG];
    __shared__ int cur[RNG];
    __shared__ float sdi[RNG];
    int t = threadIdx.x, r = blockIdx.x;
    if (t < RNG) cnt[t] = 0;
    __syncthreads();
    int lo = gbase[r * 8], hi = gbase[r * 8 + 8];
    for (int i = lo + t; i < hi; i += TPB)
        atomicAdd(&cnt[gbuf[i] & (RNG - 1)], 1);
    __syncthreads();
    if (t < RNG) offs[t] = cnt[t];
    __syncthreads();
    for (int off = 1; off < RNG; off <<= 1) {     // Hillis-Steele inclusive scan
        int v = 0;
        if (t < RNG && t >= off) v = offs[t - off];
        __syncthreads();
        if (t < RNG) offs[t] += v;
        __syncthreads();
    }
    if (t < RNG) {
        int ex = offs[t] - cnt[t];                // exclusive
        cur[t] = ex;
        float di = rsqrtf((float)cnt[t] + 1.0f);  // +1 self-loop
        sdi[t] = di;
        int n = r * RNG + t;
        if (n < N) { start[n] = lo + ex; dinv[n] = di; }
    }
    if (r == 0 && t == 0) start[N] = E;           // CSR sentinel
    __syncthreads();
    for (int i = lo + t; i < hi; i += TPB) {
        unsigned p = gbuf[i];
        int pos = lo + atomicAdd(&cur[p & (RNG - 1)], 1);
        bucketS[pos] = (int)(p >> RSH);
    }
    // fused: hsx[n][:] = fp16(dinv[n] * x[n][:]) — 128 nodes x 8 half2
    for (int idx = t; idx < RNG * 8; idx += TPB) {
        int ln = idx >> 3, f2 = idx & 7;
        int n = r * RNG + ln;
        if (n < N) {
            float2 xv = ((const float2*)x)[(size_t)n * 8 + f2];
            float dn = sdi[ln];
            hsx[(size_t)n * 8 + f2] = __floats2half2_rn(xv.x * dn, xv.y * dn);
        }
    }
}

// layer 1 + projection: wave handles 4 nodes. Per node:
//   gather16 (16 strands x uint2) -> agg16 -> GEMM 16->64 + relu + dinv
//   -> dot vs Wf (LDS, pad 17) -> z[n] fp16[16]
__global__ void k_l1f(const int* __restrict__ bucketS, const int* __restrict__ start,
                      const uint2* __restrict__ hsx, const float* __restrict__ W1,
                      const float* __restrict__ b1, const float* __restrict__ Wf,
                      const float* __restrict__ dinv, __half2* __restrict__ z, int N) {
    __shared__ float w1[16 * 64];                 // [k][j], 2-way banks only
    __shared__ float wfp[64 * 17];                // [j][o] padded -> 2-way only
    __shared__ float sb1[64];
    __shared__ float aggrow[4][16];
    __shared__ float vrow[4][64];
    int t = threadIdx.x;
    for (int i = t; i < 16 * 64; i += TPB) w1[i] = W1[i];
    for (int i = t; i < 64 * 16; i += TPB) wfp[(i >> 4) * 17 + (i & 15)] = Wf[i];
    if (t < 64) sb1[t] = b1[t];
    __syncthreads();
    int wid = t >> 6, lane = t & 63;
    int g = lane >> 2, q = lane & 3;              // 16 strands x 4 uint2 slots
    int part = lane >> 4, o = lane & 15;
#pragma unroll
    for (int nn = 0; nn < 4; nn++) {
        int n = (blockIdx.x * 4 + wid) * 4 + nn;
        if (n >= N) continue;
        int base = start[n], d = start[n + 1] - base;
        float a[4] = {0.f, 0.f, 0.f, 0.f};
        if (g == 0) acc4(a, hsx[(size_t)n * 4 + q]);      // self-loop
        for (int k = g; k < d; k += 16)
            acc4(a, hsx[(size_t)bucketS[base + k] * 4 + q]);
#pragma unroll
        for (int m = 4; m <= 32; m <<= 1)
#pragma unroll
            for (int i = 0; i < 4; i++) a[i] += __shfl_xor(a[i], m);
        if (g == 0) {
#pragma unroll
            for (int i = 0; i < 4; i++) aggrow[wid][q * 4 + i] = a[i];
        }
        // wave-coherent LDS round-trip (same wave wrote aggrow[wid])
        float dn = dinv[n];
        float v = 0.f;
#pragma unroll
        for (int k = 0; k < 16; k++) v += aggrow[wid][k] * w1[k * 64 + lane];
        v = fmaxf(dn * v + sb1[lane], 0.f) * dn;  // h1*dinv, lane j holds v_j
        vrow[wid][lane] = v;
        // z[o] = sum_j v_j * Wf[j][o] : lane (part,o) does 16 j's, reduce 2 stages
        float s = 0.f;
#pragma unroll
        for (int jj = 0; jj < 16; jj++)
            s += vrow[wid][part * 16 + jj] * wfp[(part * 16 + jj) * 17 + o];
        s += __shfl_xor(s, 16);
        s += __shfl_xor(s, 32);
        float pv = __shfl(s, lane | 1);           // even lane grabs odd neighbor
        if (part == 0 && !(lane & 1))
            z[(size_t)n * 8 + (o >> 1)] = __floats2half2_rn(s, pv);
    }
}

// layer 2 aggregation of projected z + bias: out = dinv*(z[n]+sum z[s]) + bf
__global__ void k_l3(const int* __restrict__ bucketS, const int* __restrict__ start,
                     const uint2* __restrict__ z, const float* __restrict__ bfv,
                     const float* __restrict__ dinv, float* __restrict__ out, int N) {
    __shared__ float sbf[16];
    int t = threadIdx.x;
    if (t < 16) sbf[t] = bfv[t];
    __syncthreads();
    int wid = t >> 6, lane = t & 63;
    int g = lane >> 2, q = lane & 3;              // 16 strands x 4 uint2 slots
#pragma unroll
    for (int nn = 0; nn < 4; nn++) {
        int n = (blockIdx.x * 4 + wid) * 4 + nn;
        if (n >= N) continue;
        int base = start[n], d = start[n + 1] - base;
        float a[4] = {0.f, 0.f, 0.f, 0.f};
        if (g == 0) acc4(a, z[(size_t)n * 4 + q]);        // self-loop
        for (int k = g; k < d; k += 16)
            acc4(a, z[(size_t)bucketS[base + k] * 4 + q]);
#pragma unroll
        for (int m = 4; m <= 32; m <<= 1)
#pragma unroll
            for (int i = 0; i < 4; i++) a[i] += __shfl_xor(a[i], m);
        if (g == 0) {
            float dn = dinv[n];
            float4 r;
            r.x = dn * a[0] + sbf[q * 4 + 0];
            r.y = dn * a[1] + sbf[q * 4 + 1];
            r.z = dn * a[2] + sbf[q * 4 + 2];
            r.w = dn * a[3] + sbf[q * 4 + 3];
            ((float4*)out)[(size_t)n * 4 + q] = r;
        }
    }
}

extern "C" void kernel_launch(void* const* d_in, const int* in_sizes, int n_in,
                              void* d_out, int out_size, void* d_ws, size_t ws_size,
                              hipStream_t stream) {
    const float* x  = (const float*)d_in[0];
    const int*   ei = (const int*)d_in[1];
    const float* W1 = (const float*)d_in[2];
    const float* b1 = (const float*)d_in[3];
    const float* W2 = (const float*)d_in[4];
    const float* b2 = (const float*)d_in[5];
    const float* WL = (const float*)d_in[6];
    const float* bL = (const float*)d_in[7];
    float* out = (float*)d_out;

    const int N  = in_sizes[0] / 16;       // 100000
    const int E  = in_sizes[1] / 2;        // 1600000
    const int C  = (N + RNG - 1) >> RSH;   // 782 ranges
    const int L  = C * 8;                  // (range, shard) cells
    const int NB = (E + EPB - 1) / EPB;    // hist/place blocks

    // ws ints: gbuf[E] | bucketS[E] | ghist[L] | gbase[L+1] | gcur[L] | start[N+1] | pad
    //    then: dinv[N] f32 | Wf[1024] | bf[16] | pad16B | hsx[8N] half2 | z[8N] half2
    int* wsi        = (int*)d_ws;
    unsigned* gbuf  = (unsigned*)wsi;
    int* bucketS    = wsi + E;
    int* ghist      = bucketS + E;
    int* gbase      = ghist + L;
    int* gcur       = gbase + L + 1;
    int* start      = gcur + L;
    size_t off      = (size_t)2 * E + 3 * (size_t)L + 1 + (N + 1);
    off = (off + 3) & ~(size_t)3;
    float* dinv  = (float*)(wsi + off);
    float* Wf    = dinv + N;
    float* bf    = Wf + 1024;
    off = off + N + 1024 + 16;
    off = (off + 3) & ~(size_t)3;                 // 16B-align fp16 section
    __half2* hsx = (__half2*)(wsi + off);         // 8N half2
    __half2* z   = (__half2*)(wsi + off + (size_t)8 * N);

    // weight fusion + ghist zeroing (precedes k_hist in stream order)
    k_wfuse<<<4, TPB, 0, stream>>>(W2, WL, b2, bL, Wf, bf, ghist, L);

    // ---- phase A: counting sort by dst-range (XCD-sharded cells) ----
    k_hist<<<NB, TPB, 0, stream>>>(ei, ghist, E, C);
    k_scan<<<1, TPB, 0, stream>>>(ghist, gbase, gcur, L);
    k_place<<<NB, TPB, 0, stream>>>(ei, gcur, gbuf, E, C);

    // ---- phase B: per-range node sort -> CSR + dinv + fp16 hsx ----
    k_sort2<<<C, TPB, 0, stream>>>(gbuf, gbase, x, bucketS, start, dinv, hsx, N, E);

    // ---- layer 1 + projection -> z fp16 [N,16] ----
    const int NBLK = (N + 15) / 16;               // 16 nodes per block (4/wave)
    k_l1f<<<NBLK, TPB, 0, stream>>>(bucketS, start, (const uint2*)hsx, W1, b1, Wf, dinv, z, N);

    // ---- layer 2 aggregation + bias -> out ----
    k_l3<<<NBLK, TPB, 0, stream>>>(bucketS, start, (const uint2*)z, bf, dinv, out, N);
}